// Round 4
// baseline (246.638 us; speedup 1.0000x reference)
//
#include <hip/hip_runtime.h>
#include <hip/hip_bf16.h>
#include <math.h>

#define BB 16
#define LL 200
#define HH 128
#define DD 64
#define QT2 8
#define NQT2 25         // 200/8 exact
#define NEGF -4294967295.0f
#define SQRTH 11.313708498984761f

// ---------------- embed ----------------
__global__ void k_embed(const int* __restrict__ log_seqs,
                        const float* __restrict__ item_emb,
                        float* __restrict__ seqs) {
    int row = blockIdx.x;
    int t = threadIdx.x;
    int id = log_seqs[row];
    float v = (id == 0) ? 0.0f : item_emb[id * HH + t] * SQRTH;
    seqs[row * HH + t] = v;
}

// ---------------- QKV projection + time-K projection, 8 rows/block ----------------
// Q = seqs@Wq^T+bq ; Kp = K+posK ; Vp = V+posV ; projK[bh,q,tt] = Q . timeK[tt]
__global__ __launch_bounds__(256) void k_qkv_proj(const float* __restrict__ seqs,
    const float* __restrict__ Wq, const float* __restrict__ bq,
    const float* __restrict__ Wk, const float* __restrict__ bk,
    const float* __restrict__ Wv, const float* __restrict__ bv,
    const float* __restrict__ posK, const float* __restrict__ posV,
    const float* __restrict__ timeK,
    float* __restrict__ Q, float* __restrict__ Kp, float* __restrict__ Vp,
    float* __restrict__ projK) {
    __shared__ float s_lds[8][HH];
    int r0g = blockIdx.x * 8;
    int b = r0g / LL, l0 = r0g % LL;
    int t = threadIdx.x;
    ((float4*)s_lds)[t] = ((const float4*)(seqs + r0g * HH))[t];
    __syncthreads();
    int c = t & 127, rg = t >> 7;
    float aq[4] = {0.f, 0.f, 0.f, 0.f};
    float ak[4] = {0.f, 0.f, 0.f, 0.f};
    float av[4] = {0.f, 0.f, 0.f, 0.f};
    const float4* wq4 = (const float4*)(Wq + c * HH);
    const float4* wk4 = (const float4*)(Wk + c * HH);
    const float4* wv4 = (const float4*)(Wv + c * HH);
#pragma unroll 4
    for (int k4 = 0; k4 < HH / 4; ++k4) {
        float4 wq = wq4[k4], wk = wk4[k4], wv = wv4[k4];
#pragma unroll
        for (int r = 0; r < 4; ++r) {
            float4 s = *(const float4*)&s_lds[rg * 4 + r][k4 * 4];
            aq[r] += s.x * wq.x + s.y * wq.y + s.z * wq.z + s.w * wq.w;
            ak[r] += s.x * wk.x + s.y * wk.y + s.z * wk.z + s.w * wk.w;
            av[r] += s.x * wv.x + s.y * wv.y + s.z * wv.z + s.w * wv.w;
        }
    }
    __syncthreads();   // all seqs reads done before overwriting s_lds with Q
#pragma unroll
    for (int r = 0; r < 4; ++r) {
        int row = r0g + rg * 4 + r;
        int l = l0 + rg * 4 + r;
        float qv = aq[r] + bq[c];
        Q[row * HH + c] = qv;
        s_lds[rg * 4 + r][c] = qv;
        Kp[row * HH + c] = ak[r] + bk[c] + posK[l * HH + c];
        Vp[row * HH + c] = av[r] + bv[c] + posV[l * HH + c];
    }
    __syncthreads();
    // phase B: projK for the 8 rows, both heads; thread = tt
    for (int tt = t; tt < 257; tt += 256) {
#pragma unroll
        for (int h = 0; h < 2; ++h) {
            float4 kr[16];
            const float4* tk = (const float4*)(timeK + tt * HH + h * DD);
#pragma unroll
            for (int d4 = 0; d4 < 16; ++d4) kr[d4] = tk[d4];
#pragma unroll
            for (int qq = 0; qq < 8; ++qq) {
                float acc = 0.f;
#pragma unroll
                for (int d4 = 0; d4 < 16; ++d4) {
                    float4 s = *(const float4*)&s_lds[qq][h * DD + d4 * 4];
                    acc += s.x * kr[d4].x + s.y * kr[d4].y + s.z * kr[d4].z + s.w * kr[d4].w;
                }
                projK[((b * 2 + h) * LL + l0 + qq) * 257 + tt] = acc;
            }
        }
    }
}

// ---------------- fused scores + softmax + hist + PV ----------------
// grid = 32 bh * 25 qtiles(8); 256 threads: tq/g = t>>5, lane = t&31
__global__ __launch_bounds__(256) void k_attn(
    const float* __restrict__ Q, const float* __restrict__ Kp, const float* __restrict__ Vp,
    const float* __restrict__ projK, const float* __restrict__ timeV,
    const int* __restrict__ tm, const int* __restrict__ log_seqs,
    float* __restrict__ attnout) {
    int bh = blockIdx.x / NQT2, qt = blockIdx.x % NQT2;
    int b = bh >> 1, h = bh & 1;
    int qlo = qt * QT2;
    __shared__ float KV[64][68];        // staging + final partial-reduce scratch
    __shared__ float S_T[200][12];      // transposed scores: S_T[k][q]
    __shared__ float hist_T[257][12];   // transposed hist:   hist_T[tt][q]
    __shared__ int pmask[LL];
    __shared__ int s_allmask;
    int t = threadIdx.x;
    int tq = t >> 5, lane = t & 31;
    int g = tq;
    int q = qlo + tq;
    int qhi = qlo + QT2 - 1;

    for (int x = t; x < LL; x += 256) pmask[x] = (log_seqs[b * LL + x] != 0);
    for (int x = t; x < 200 * 12; x += 256) ((float*)S_T)[x] = NEGF;
    for (int x = t; x < 257 * 12; x += 256) ((float*)hist_T)[x] = 0.f;
    if (t == 0) s_allmask = 0;

    // Q row into registers (broadcast loads, L1/L2-served)
    float4 qreg[16];
    {
        const float4* qp = (const float4*)(Q + (b * LL + q) * HH + h * DD);
#pragma unroll
        for (int d4 = 0; d4 < 16; ++d4) qreg[d4] = qp[d4];
    }
    __syncthreads();

    const int* tmrow = tm + (b * LL + q) * LL;
    const float* projrow = projK + (bh * LL + q) * 257;

    // phase 1: scores into S_T
    int nkt = (qhi >> 6) + 1;
    for (int kt = 0; kt < nkt; ++kt) {
        int kbase = kt * 64;
        for (int x = t; x < 64 * 16; x += 256) {
            int i = x >> 4, d4 = x & 15;
            int k = kbase + i;
            if (k < LL)
                *(float4*)&KV[i][d4 * 4] =
                    ((const float4*)(Kp + (b * LL + k) * HH + h * DD))[d4];
        }
        __syncthreads();
#pragma unroll
        for (int j = 0; j < 2; ++j) {
            int kk = lane + 32 * j;
            int k = kbase + kk;
            if (k <= q && pmask[k]) {
                float acc = 0.f;
#pragma unroll
                for (int d4 = 0; d4 < 16; ++d4) {
                    float4 kv = *(const float4*)&KV[kk][d4 * 4];
                    acc += qreg[d4].x * kv.x + qreg[d4].y * kv.y +
                           qreg[d4].z * kv.z + qreg[d4].w * kv.w;
                }
                S_T[k][tq] = (acc + projrow[tmrow[k]]) * 0.125f;
            }
        }
        __syncthreads();
    }

    // phase 2: softmax (32 lanes per q row, on S_T columns)
    float mx = -INFINITY;
    for (int k = lane; k < LL; k += 32) mx = fmaxf(mx, S_T[k][tq]);
    mx = fmaxf(mx, __shfl_xor(mx, 1, 64));
    mx = fmaxf(mx, __shfl_xor(mx, 2, 64));
    mx = fmaxf(mx, __shfl_xor(mx, 4, 64));
    mx = fmaxf(mx, __shfl_xor(mx, 8, 64));
    mx = fmaxf(mx, __shfl_xor(mx, 16, 64));
    bool allmask = (mx == NEGF);
    float sum = 0.f;
    for (int k = lane; k < LL; k += 32) {
        float e = __expf(S_T[k][tq] - mx);
        S_T[k][tq] = e;
        sum += e;
    }
    sum += __shfl_xor(sum, 1, 64);
    sum += __shfl_xor(sum, 2, 64);
    sum += __shfl_xor(sum, 4, 64);
    sum += __shfl_xor(sum, 8, 64);
    sum += __shfl_xor(sum, 16, 64);
    float inv = 1.0f / sum;
    for (int k = lane; k < LL; k += 32) S_T[k][tq] *= inv;
    if (allmask && lane == 0) s_allmask = 1;

    // hist_T[tt][q] = sum_k A[q,k] [tm==tt]
    int klim = allmask ? LL : (q + 1);
    for (int k = lane; k < klim; k += 32)
        atomicAdd(&hist_T[tmrow[k]][tq], S_T[k][tq]);
    __syncthreads();
    int vtiles = s_allmask ? 4 : nkt;

    // phase 3: PV — groups stripe over source rows, acc[8q][2d] in registers
    float a00=0.f,a01=0.f,a10=0.f,a11=0.f,a20=0.f,a21=0.f,a30=0.f,a31=0.f;
    float a40=0.f,a41=0.f,a50=0.f,a51=0.f,a60=0.f,a61=0.f,a70=0.f,a71=0.f;
    for (int c = 0; c < 9; ++c) {
        if (c < 4 && c >= vtiles) continue;
        __syncthreads();                       // previous chunk fully consumed
        int kend;
        const float* wtab;
        if (c < 4) {
            int kbase = c * 64;
            for (int x = t; x < 64 * 16; x += 256) {
                int i = x >> 4, d4 = x & 15;
                int k = kbase + i;
                if (k < LL)
                    *(float4*)&KV[i][d4 * 4] =
                        ((const float4*)(Vp + (b * LL + k) * HH + h * DD))[d4];
            }
            kend = LL - kbase; if (kend > 64) kend = 64;
            wtab = &S_T[kbase][0];
        } else {
            int tb = (c - 4) * 64;
            for (int x = t; x < 64 * 16; x += 256) {
                int i = x >> 4, d4 = x & 15;
                int tt = tb + i;
                if (tt < 257)
                    *(float4*)&KV[i][d4 * 4] =
                        ((const float4*)(timeV + tt * HH + h * DD))[d4];
            }
            kend = 257 - tb; if (kend > 64) kend = 64;
            wtab = &hist_T[tb][0];
        }
        __syncthreads();
        for (int i = g; i < kend; i += 8) {
            float2 vv = *(const float2*)&KV[i][lane * 2];
            const float* wr = wtab + i * 12;
            float4 w0 = *(const float4*)wr;
            float4 w1 = *(const float4*)(wr + 4);
            a00 += w0.x * vv.x; a01 += w0.x * vv.y;
            a10 += w0.y * vv.x; a11 += w0.y * vv.y;
            a20 += w0.z * vv.x; a21 += w0.z * vv.y;
            a30 += w0.w * vv.x; a31 += w0.w * vv.y;
            a40 += w1.x * vv.x; a41 += w1.x * vv.y;
            a50 += w1.y * vv.x; a51 += w1.y * vv.y;
            a60 += w1.z * vv.x; a61 += w1.z * vv.y;
            a70 += w1.w * vv.x; a71 += w1.w * vv.y;
        }
    }
    __syncthreads();
    // reduce partials across the 8 groups via KV scratch (8*8*64 = 4096 <= 64*68)
    float* part = &KV[0][0];
    part[g * 512 + 0 * 64 + lane * 2] = a00; part[g * 512 + 0 * 64 + lane * 2 + 1] = a01;
    part[g * 512 + 1 * 64 + lane * 2] = a10; part[g * 512 + 1 * 64 + lane * 2 + 1] = a11;
    part[g * 512 + 2 * 64 + lane * 2] = a20; part[g * 512 + 2 * 64 + lane * 2 + 1] = a21;
    part[g * 512 + 3 * 64 + lane * 2] = a30; part[g * 512 + 3 * 64 + lane * 2 + 1] = a31;
    part[g * 512 + 4 * 64 + lane * 2] = a40; part[g * 512 + 4 * 64 + lane * 2 + 1] = a41;
    part[g * 512 + 5 * 64 + lane * 2] = a50; part[g * 512 + 5 * 64 + lane * 2 + 1] = a51;
    part[g * 512 + 6 * 64 + lane * 2] = a60; part[g * 512 + 6 * 64 + lane * 2 + 1] = a61;
    part[g * 512 + 7 * 64 + lane * 2] = a70; part[g * 512 + 7 * 64 + lane * 2 + 1] = a71;
    __syncthreads();
    {
        float ox = 0.f, oy = 0.f;
#pragma unroll
        for (int gg = 0; gg < 8; ++gg) {
            ox += part[gg * 512 + tq * 64 + lane * 2];
            oy += part[gg * 512 + tq * 64 + lane * 2 + 1];
        }
        float2 o = make_float2(ox, oy);
        *(float2*)(attnout + (b * LL + q) * HH + h * DD + lane * 2) = o;
    }
}

// ---------------- fused: s1 = LN1(seqs+AO); seqs = LN2(s1 + FFN(s1)) * keep ----------------
__global__ __launch_bounds__(256) void k_ffn_full(
    float* __restrict__ seqs, const float* __restrict__ AO,
    const float* __restrict__ g1, const float* __restrict__ be1,
    const float* __restrict__ W1, const float* __restrict__ b1,
    const float* __restrict__ W2, const float* __restrict__ b2,
    const float* __restrict__ g2, const float* __restrict__ be2,
    const int* __restrict__ log_seqs) {
    __shared__ float s_lds[8][HH];
    __shared__ float h_lds[8][HH];
    int r0g = blockIdx.x * 8;
    int t = threadIdx.x;
    {
        float4 a = ((const float4*)(seqs + r0g * HH))[t];
        float4 o = ((const float4*)(AO + r0g * HH))[t];
        a.x += o.x; a.y += o.y; a.z += o.z; a.w += o.w;
        ((float4*)s_lds)[t] = a;
    }
    __syncthreads();
    int w = t >> 6, lane = t & 63;
    int lrow = w * 2 + (lane >> 5), cl = lane & 31;
    // LN1 in-place on s_lds
    {
        float sm = 0.f;
#pragma unroll
        for (int j = 0; j < 4; ++j) sm += s_lds[lrow][cl + 32 * j];
        sm += __shfl_xor(sm, 1, 64);
        sm += __shfl_xor(sm, 2, 64);
        sm += __shfl_xor(sm, 4, 64);
        sm += __shfl_xor(sm, 8, 64);
        sm += __shfl_xor(sm, 16, 64);
        float mean = sm * (1.0f / HH);
        float vr = 0.f;
#pragma unroll
        for (int j = 0; j < 4; ++j) {
            float d = s_lds[lrow][cl + 32 * j] - mean;
            vr += d * d;
        }
        vr += __shfl_xor(vr, 1, 64);
        vr += __shfl_xor(vr, 2, 64);
        vr += __shfl_xor(vr, 4, 64);
        vr += __shfl_xor(vr, 8, 64);
        vr += __shfl_xor(vr, 16, 64);
        float rstd = rsqrtf(vr * (1.0f / HH) + 1e-8f);
#pragma unroll
        for (int j = 0; j < 4; ++j) {
            int c = cl + 32 * j;
            s_lds[lrow][c] = (s_lds[lrow][c] - mean) * rstd * g1[c] + be1[c];
        }
    }
    __syncthreads();
    // GEMM1 + relu
    int c = t & 127, rg = t >> 7;
    float acc[4] = {0.f, 0.f, 0.f, 0.f};
    const float4* w14 = (const float4*)(W1 + c * HH);
#pragma unroll 4
    for (int k4 = 0; k4 < HH / 4; ++k4) {
        float4 ww = w14[k4];
#pragma unroll
        for (int r = 0; r < 4; ++r) {
            float4 s = *(const float4*)&s_lds[rg * 4 + r][k4 * 4];
            acc[r] += s.x * ww.x + s.y * ww.y + s.z * ww.z + s.w * ww.w;
        }
    }
#pragma unroll
    for (int r = 0; r < 4; ++r) h_lds[rg * 4 + r][c] = fmaxf(acc[r] + b1[c], 0.f);
    __syncthreads();
    // GEMM2 into registers
#pragma unroll
    for (int r = 0; r < 4; ++r) acc[r] = 0.f;
    const float4* w24 = (const float4*)(W2 + c * HH);
#pragma unroll 4
    for (int k4 = 0; k4 < HH / 4; ++k4) {
        float4 ww = w24[k4];
#pragma unroll
        for (int r = 0; r < 4; ++r) {
            float4 s = *(const float4*)&h_lds[rg * 4 + r][k4 * 4];
            acc[r] += s.x * ww.x + s.y * ww.y + s.z * ww.z + s.w * ww.w;
        }
    }
    __syncthreads();   // h_lds reads done; reuse for x2 = s1 + ffn
#pragma unroll
    for (int r = 0; r < 4; ++r)
        h_lds[rg * 4 + r][c] = s_lds[rg * 4 + r][c] + acc[r] + b2[c];
    __syncthreads();
    // LN2 + keep, write seqs
    {
        float sm = 0.f;
#pragma unroll
        for (int j = 0; j < 4; ++j) sm += h_lds[lrow][cl + 32 * j];
        sm += __shfl_xor(sm, 1, 64);
        sm += __shfl_xor(sm, 2, 64);
        sm += __shfl_xor(sm, 4, 64);
        sm += __shfl_xor(sm, 8, 64);
        sm += __shfl_xor(sm, 16, 64);
        float mean = sm * (1.0f / HH);
        float vr = 0.f;
#pragma unroll
        for (int j = 0; j < 4; ++j) {
            float d = h_lds[lrow][cl + 32 * j] - mean;
            vr += d * d;
        }
        vr += __shfl_xor(vr, 1, 64);
        vr += __shfl_xor(vr, 2, 64);
        vr += __shfl_xor(vr, 4, 64);
        vr += __shfl_xor(vr, 8, 64);
        vr += __shfl_xor(vr, 16, 64);
        float rstd = rsqrtf(vr * (1.0f / HH) + 1e-8f);
        float keep = (log_seqs[r0g + lrow] != 0) ? 1.0f : 0.0f;
#pragma unroll
        for (int j = 0; j < 4; ++j) {
            int cc = cl + 32 * j;
            float y = (h_lds[lrow][cc] - mean) * rstd * g2[cc] + be2[cc];
            seqs[(r0g + lrow) * HH + cc] = y * keep;
        }
    }
}

// ---------------- final LN + logits ----------------
__global__ void k_final(const float* __restrict__ seqs,
                        const float* __restrict__ lnf_g, const float* __restrict__ lnf_b,
                        const float* __restrict__ item_emb,
                        const int* __restrict__ pos_seqs, const int* __restrict__ neg_seqs,
                        float* __restrict__ out) {
    __shared__ float red[2];
    int row = blockIdx.x;
    int t = threadIdx.x;
    float x = seqs[row * HH + t];
    float m = x;
    m += __shfl_xor(m, 1, 64); m += __shfl_xor(m, 2, 64); m += __shfl_xor(m, 4, 64);
    m += __shfl_xor(m, 8, 64); m += __shfl_xor(m, 16, 64); m += __shfl_xor(m, 32, 64);
    if ((t & 63) == 0) red[t >> 6] = m;
    __syncthreads();
    m = (red[0] + red[1]) * (1.0f / HH);
    float d = x - m;
    __syncthreads();
    float v2 = d * d;
    v2 += __shfl_xor(v2, 1, 64); v2 += __shfl_xor(v2, 2, 64); v2 += __shfl_xor(v2, 4, 64);
    v2 += __shfl_xor(v2, 8, 64); v2 += __shfl_xor(v2, 16, 64); v2 += __shfl_xor(v2, 32, 64);
    if ((t & 63) == 0) red[t >> 6] = v2;
    __syncthreads();
    float var = (red[0] + red[1]) * (1.0f / HH);
    float lf = d * rsqrtf(var + 1e-8f) * lnf_g[t] + lnf_b[t];
    int pid = pos_seqs[row];
    int nid = neg_seqs[row];
    float pp = lf * item_emb[pid * HH + t];
    float nn = lf * item_emb[nid * HH + t];
    __syncthreads();
    float ps = pp;
    ps += __shfl_xor(ps, 1, 64); ps += __shfl_xor(ps, 2, 64); ps += __shfl_xor(ps, 4, 64);
    ps += __shfl_xor(ps, 8, 64); ps += __shfl_xor(ps, 16, 64); ps += __shfl_xor(ps, 32, 64);
    if ((t & 63) == 0) red[t >> 6] = ps;
    __syncthreads();
    float ptot = red[0] + red[1];
    __syncthreads();
    float ns = nn;
    ns += __shfl_xor(ns, 1, 64); ns += __shfl_xor(ns, 2, 64); ns += __shfl_xor(ns, 4, 64);
    ns += __shfl_xor(ns, 8, 64); ns += __shfl_xor(ns, 16, 64); ns += __shfl_xor(ns, 32, 64);
    if ((t & 63) == 0) red[t >> 6] = ns;
    __syncthreads();
    float ntot = red[0] + red[1];
    if (t == 0) {
        out[row] = ptot;
        out[BB * LL + row] = ntot;
    }
}

extern "C" void kernel_launch(void* const* d_in, const int* in_sizes, int n_in,
                              void* d_out, int out_size, void* d_ws, size_t ws_size,
                              hipStream_t stream) {
    const int* log_seqs = (const int*)d_in[1];
    const int* tm       = (const int*)d_in[2];
    const int* pos_seqs = (const int*)d_in[3];
    const int* neg_seqs = (const int*)d_in[4];
    const float* item_emb = (const float*)d_in[5];
    const float* posK   = (const float*)d_in[6];
    const float* posV   = (const float*)d_in[7];
    const float* timeK  = (const float*)d_in[8];
    const float* timeV  = (const float*)d_in[9];
    const float* Wq = (const float*)d_in[10];
    const float* bq = (const float*)d_in[11];
    const float* Wk = (const float*)d_in[12];
    const float* bk = (const float*)d_in[13];
    const float* Wv = (const float*)d_in[14];
    const float* bv = (const float*)d_in[15];
    const float* ln1_g = (const float*)d_in[16];
    const float* ln1_b = (const float*)d_in[17];
    const float* W1 = (const float*)d_in[18];
    const float* b1 = (const float*)d_in[19];
    const float* W2 = (const float*)d_in[20];
    const float* b2 = (const float*)d_in[21];
    const float* ln2_g = (const float*)d_in[22];
    const float* ln2_b = (const float*)d_in[23];
    const float* lnf_g = (const float*)d_in[24];
    const float* lnf_b = (const float*)d_in[25];

    float* ws    = (float*)d_ws;
    float* seqs  = ws;                   // 409600
    float* Qb    = seqs + 409600;
    float* Kpb   = Qb + 409600;
    float* Vpb   = Kpb + 409600;
    float* AO    = Vpb + 409600;
    float* projK = AO + 409600;          // 32*200*257 = 1,644,800

    k_embed<<<BB * LL, HH, 0, stream>>>(log_seqs, item_emb, seqs);
    for (int i = 0; i < 2; ++i) {
        k_qkv_proj<<<BB * LL / 8, 256, 0, stream>>>(seqs,
            Wq + i * HH * HH, bq + i * HH,
            Wk + i * HH * HH, bk + i * HH,
            Wv + i * HH * HH, bv + i * HH,
            posK, posV, timeK, Qb, Kpb, Vpb, projK);
        k_attn<<<32 * NQT2, 256, 0, stream>>>(Qb, Kpb, Vpb, projK, timeV,
                                              tm, log_seqs, AO);
        k_ffn_full<<<BB * LL / 8, 256, 0, stream>>>(seqs, AO,
            ln1_g + i * HH, ln1_b + i * HH,
            W1 + i * HH * HH, b1 + i * HH,
            W2 + i * HH * HH, b2 + i * HH,
            ln2_g + i * HH, ln2_b + i * HH, log_seqs);
    }
    k_final<<<BB * LL, HH, 0, stream>>>(seqs, lnf_g, lnf_b, item_emb,
                                        pos_seqs, neg_seqs, (float*)d_out);
}

// Round 5
// 206.311 us; speedup vs baseline: 1.1955x; 1.1955x over previous
//
#include <hip/hip_runtime.h>
#include <hip/hip_bf16.h>
#include <math.h>

#define BB 16
#define LL 200
#define HH 128
#define DD 64
#define QT2 8
#define NQT2 25         // 200/8 exact
#define NEGF -4294967295.0f
#define SQRTH 11.313708498984761f

// ---------------- QKV projection (16 rows/block, 512 threads), optional embed ----------------
// layer 0: s = item_emb[log_seqs]*sqrtH (also written to seqs); else s = seqs.
// Q = s@Wq^T+bq ; Kp = s@Wk^T+bk+posK[l] ; Vp = s@Wv^T+bv+posV[l]
__global__ __launch_bounds__(512) void k_qkv(float* __restrict__ seqs,
    const int* __restrict__ log_seqs, const float* __restrict__ item_emb, int do_embed,
    const float* __restrict__ Wq, const float* __restrict__ bq,
    const float* __restrict__ Wk, const float* __restrict__ bk,
    const float* __restrict__ Wv, const float* __restrict__ bv,
    const float* __restrict__ posK, const float* __restrict__ posV,
    float* __restrict__ Q, float* __restrict__ Kp, float* __restrict__ Vp) {
    __shared__ float s_lds[16][HH];
    int r0g = blockIdx.x * 16;
    int t = threadIdx.x;
    if (do_embed) {
        int r = t >> 5, d4 = t & 31;          // 16 rows x 32 float4
        int id = log_seqs[r0g + r];
        float4 v = make_float4(0.f, 0.f, 0.f, 0.f);
        if (id != 0) {
            v = ((const float4*)(item_emb + id * HH))[d4];
            v.x *= SQRTH; v.y *= SQRTH; v.z *= SQRTH; v.w *= SQRTH;
        }
        *(float4*)&s_lds[r][d4 * 4] = v;
        ((float4*)(seqs + r0g * HH))[t] = v;
    } else {
        ((float4*)s_lds)[t] = ((const float4*)(seqs + r0g * HH))[t];
    }
    __syncthreads();
    int c = t & 127, rg = t >> 7;
    float aq[4] = {0.f, 0.f, 0.f, 0.f};
    float ak[4] = {0.f, 0.f, 0.f, 0.f};
    float av[4] = {0.f, 0.f, 0.f, 0.f};
    const float4* wq4 = (const float4*)(Wq + c * HH);
    const float4* wk4 = (const float4*)(Wk + c * HH);
    const float4* wv4 = (const float4*)(Wv + c * HH);
#pragma unroll 4
    for (int k4 = 0; k4 < HH / 4; ++k4) {
        float4 wq = wq4[k4], wk = wk4[k4], wv = wv4[k4];
#pragma unroll
        for (int r = 0; r < 4; ++r) {
            float4 s = *(const float4*)&s_lds[rg * 4 + r][k4 * 4];
            aq[r] += s.x * wq.x + s.y * wq.y + s.z * wq.z + s.w * wq.w;
            ak[r] += s.x * wk.x + s.y * wk.y + s.z * wk.z + s.w * wk.w;
            av[r] += s.x * wv.x + s.y * wv.y + s.z * wv.z + s.w * wv.w;
        }
    }
#pragma unroll
    for (int r = 0; r < 4; ++r) {
        int row = r0g + rg * 4 + r;
        int l = row % LL;
        Q[row * HH + c]  = aq[r] + bq[c];
        Kp[row * HH + c] = ak[r] + bk[c] + posK[l * HH + c];
        Vp[row * HH + c] = av[r] + bv[c] + posV[l * HH + c];
    }
}

// ---------------- fused timeK-proj + scores + softmax + hist + PV ----------------
// grid = 32 bh * 25 qtiles(8); 256 threads: tq/g = t>>5, lane = t&31
__global__ __launch_bounds__(256) void k_attn(
    const float* __restrict__ Q, const float* __restrict__ Kp, const float* __restrict__ Vp,
    const float* __restrict__ timeK, const float* __restrict__ timeV,
    const int* __restrict__ tm, const int* __restrict__ log_seqs,
    float* __restrict__ attnout) {
    int bh = blockIdx.x / NQT2, qt = blockIdx.x % NQT2;
    int b = bh >> 1, h = bh & 1;
    int qlo = qt * QT2;
    __shared__ float KV[64][68];        // staging + final partial-reduce scratch
    __shared__ float S_T[200][12];      // transposed scores: S_T[k][q]
    __shared__ float hist_T[257][12];   // transposed hist:   hist_T[tt][q]
    __shared__ float proj_T[257][8];    // proj_T[tt][q] = Q[q] . timeK[tt]
    __shared__ int pmask[LL];
    __shared__ int s_allmask;
    int t = threadIdx.x;
    int tq = t >> 5, lane = t & 31;
    int g = tq;
    int q = qlo + tq;
    int qhi = qlo + QT2 - 1;

    for (int x = t; x < LL; x += 256) pmask[x] = (log_seqs[b * LL + x] != 0);
    for (int x = t; x < 200 * 12; x += 256) ((float*)S_T)[x] = NEGF;
    for (int x = t; x < 257 * 12; x += 256) ((float*)hist_T)[x] = 0.f;
    if (t == 0) s_allmask = 0;

    // Q row into registers (broadcast loads, L2-served)
    float4 qreg[16];
    {
        const float4* qp = (const float4*)(Q + (b * LL + q) * HH + h * DD);
#pragma unroll
        for (int d4 = 0; d4 < 16; ++d4) qreg[d4] = qp[d4];
    }
    __syncthreads();

    const int* tmrow = tm + (b * LL + q) * LL;

    // phase 0: proj_T[tt][tq] = qreg . timeK[tt] (5 chunks of 64 through KV)
    for (int c = 0; c < 5; ++c) {
        int base = c * 64;
        for (int x = t; x < 64 * 16; x += 256) {
            int i = x >> 4, d4 = x & 15;
            int tt = base + i;
            if (tt < 257)
                *(float4*)&KV[i][d4 * 4] =
                    ((const float4*)(timeK + tt * HH + h * DD))[d4];
        }
        __syncthreads();
#pragma unroll
        for (int j = 0; j < 2; ++j) {
            int ttl = lane + 32 * j;
            int tt = base + ttl;
            if (tt < 257) {
                float acc = 0.f;
#pragma unroll
                for (int d4 = 0; d4 < 16; ++d4) {
                    float4 kv = *(const float4*)&KV[ttl][d4 * 4];
                    acc += qreg[d4].x * kv.x + qreg[d4].y * kv.y +
                           qreg[d4].z * kv.z + qreg[d4].w * kv.w;
                }
                proj_T[tt][tq] = acc;
            }
        }
        __syncthreads();
    }

    // phase 1: scores into S_T
    int nkt = (qhi >> 6) + 1;
    for (int kt = 0; kt < nkt; ++kt) {
        int kbase = kt * 64;
        for (int x = t; x < 64 * 16; x += 256) {
            int i = x >> 4, d4 = x & 15;
            int k = kbase + i;
            if (k < LL)
                *(float4*)&KV[i][d4 * 4] =
                    ((const float4*)(Kp + (b * LL + k) * HH + h * DD))[d4];
        }
        __syncthreads();
#pragma unroll
        for (int j = 0; j < 2; ++j) {
            int kk = lane + 32 * j;
            int k = kbase + kk;
            if (k <= q && pmask[k]) {
                float acc = 0.f;
#pragma unroll
                for (int d4 = 0; d4 < 16; ++d4) {
                    float4 kv = *(const float4*)&KV[kk][d4 * 4];
                    acc += qreg[d4].x * kv.x + qreg[d4].y * kv.y +
                           qreg[d4].z * kv.z + qreg[d4].w * kv.w;
                }
                S_T[k][tq] = (acc + proj_T[tmrow[k]][tq]) * 0.125f;
            }
        }
        __syncthreads();
    }

    // phase 2: softmax (32 lanes per q row, on S_T columns)
    float mx = -INFINITY;
    for (int k = lane; k < LL; k += 32) mx = fmaxf(mx, S_T[k][tq]);
    mx = fmaxf(mx, __shfl_xor(mx, 1, 64));
    mx = fmaxf(mx, __shfl_xor(mx, 2, 64));
    mx = fmaxf(mx, __shfl_xor(mx, 4, 64));
    mx = fmaxf(mx, __shfl_xor(mx, 8, 64));
    mx = fmaxf(mx, __shfl_xor(mx, 16, 64));
    bool allmask = (mx == NEGF);
    float sum = 0.f;
    for (int k = lane; k < LL; k += 32) {
        float e = __expf(S_T[k][tq] - mx);
        S_T[k][tq] = e;
        sum += e;
    }
    sum += __shfl_xor(sum, 1, 64);
    sum += __shfl_xor(sum, 2, 64);
    sum += __shfl_xor(sum, 4, 64);
    sum += __shfl_xor(sum, 8, 64);
    sum += __shfl_xor(sum, 16, 64);
    float inv = 1.0f / sum;
    for (int k = lane; k < LL; k += 32) S_T[k][tq] *= inv;
    if (allmask && lane == 0) s_allmask = 1;

    // hist_T[tt][q] = sum_k A[q,k] [tm==tt]
    int klim = allmask ? LL : (q + 1);
    for (int k = lane; k < klim; k += 32)
        atomicAdd(&hist_T[tmrow[k]][tq], S_T[k][tq]);
    __syncthreads();
    int vtiles = s_allmask ? 4 : nkt;

    // phase 3: PV — groups stripe over source rows, acc[8q][2d] in registers
    float a00=0.f,a01=0.f,a10=0.f,a11=0.f,a20=0.f,a21=0.f,a30=0.f,a31=0.f;
    float a40=0.f,a41=0.f,a50=0.f,a51=0.f,a60=0.f,a61=0.f,a70=0.f,a71=0.f;
    for (int c = 0; c < 9; ++c) {
        if (c < 4 && c >= vtiles) continue;
        __syncthreads();                       // previous chunk fully consumed
        int kend;
        const float* wtab;
        if (c < 4) {
            int kbase = c * 64;
            for (int x = t; x < 64 * 16; x += 256) {
                int i = x >> 4, d4 = x & 15;
                int k = kbase + i;
                if (k < LL)
                    *(float4*)&KV[i][d4 * 4] =
                        ((const float4*)(Vp + (b * LL + k) * HH + h * DD))[d4];
            }
            kend = LL - kbase; if (kend > 64) kend = 64;
            wtab = &S_T[kbase][0];
        } else {
            int tb = (c - 4) * 64;
            for (int x = t; x < 64 * 16; x += 256) {
                int i = x >> 4, d4 = x & 15;
                int tt = tb + i;
                if (tt < 257)
                    *(float4*)&KV[i][d4 * 4] =
                        ((const float4*)(timeV + tt * HH + h * DD))[d4];
            }
            kend = 257 - tb; if (kend > 64) kend = 64;
            wtab = &hist_T[tb][0];
        }
        __syncthreads();
        for (int i = g; i < kend; i += 8) {
            float2 vv = *(const float2*)&KV[i][lane * 2];
            const float* wr = wtab + i * 12;
            float4 w0 = *(const float4*)wr;
            float4 w1 = *(const float4*)(wr + 4);
            a00 += w0.x * vv.x; a01 += w0.x * vv.y;
            a10 += w0.y * vv.x; a11 += w0.y * vv.y;
            a20 += w0.z * vv.x; a21 += w0.z * vv.y;
            a30 += w0.w * vv.x; a31 += w0.w * vv.y;
            a40 += w1.x * vv.x; a41 += w1.x * vv.y;
            a50 += w1.y * vv.x; a51 += w1.y * vv.y;
            a60 += w1.z * vv.x; a61 += w1.z * vv.y;
            a70 += w1.w * vv.x; a71 += w1.w * vv.y;
        }
    }
    __syncthreads();
    // reduce partials across the 8 groups via KV scratch (8*8*64 = 4096 <= 64*68)
    float* part = &KV[0][0];
    part[g * 512 + 0 * 64 + lane * 2] = a00; part[g * 512 + 0 * 64 + lane * 2 + 1] = a01;
    part[g * 512 + 1 * 64 + lane * 2] = a10; part[g * 512 + 1 * 64 + lane * 2 + 1] = a11;
    part[g * 512 + 2 * 64 + lane * 2] = a20; part[g * 512 + 2 * 64 + lane * 2 + 1] = a21;
    part[g * 512 + 3 * 64 + lane * 2] = a30; part[g * 512 + 3 * 64 + lane * 2 + 1] = a31;
    part[g * 512 + 4 * 64 + lane * 2] = a40; part[g * 512 + 4 * 64 + lane * 2 + 1] = a41;
    part[g * 512 + 5 * 64 + lane * 2] = a50; part[g * 512 + 5 * 64 + lane * 2 + 1] = a51;
    part[g * 512 + 6 * 64 + lane * 2] = a60; part[g * 512 + 6 * 64 + lane * 2 + 1] = a61;
    part[g * 512 + 7 * 64 + lane * 2] = a70; part[g * 512 + 7 * 64 + lane * 2 + 1] = a71;
    __syncthreads();
    {
        float ox = 0.f, oy = 0.f;
#pragma unroll
        for (int gg = 0; gg < 8; ++gg) {
            ox += part[gg * 512 + tq * 64 + lane * 2];
            oy += part[gg * 512 + tq * 64 + lane * 2 + 1];
        }
        *(float2*)(attnout + (b * LL + q) * HH + h * DD + lane * 2) =
            make_float2(ox, oy);
    }
}

// ---------------- fused: s1 = LN1(seqs+AO); seqs = LN2(s1 + FFN(s1)) * keep ----------------
__global__ __launch_bounds__(256) void k_ffn_full(
    float* __restrict__ seqs, const float* __restrict__ AO,
    const float* __restrict__ g1, const float* __restrict__ be1,
    const float* __restrict__ W1, const float* __restrict__ b1,
    const float* __restrict__ W2, const float* __restrict__ b2,
    const float* __restrict__ g2, const float* __restrict__ be2,
    const int* __restrict__ log_seqs) {
    __shared__ float s_lds[8][HH];
    __shared__ float h_lds[8][HH];
    int r0g = blockIdx.x * 8;
    int t = threadIdx.x;
    {
        float4 a = ((const float4*)(seqs + r0g * HH))[t];
        float4 o = ((const float4*)(AO + r0g * HH))[t];
        a.x += o.x; a.y += o.y; a.z += o.z; a.w += o.w;
        ((float4*)s_lds)[t] = a;
    }
    __syncthreads();
    int w = t >> 6, lane = t & 63;
    int lrow = w * 2 + (lane >> 5), cl = lane & 31;
    // LN1 in-place on s_lds
    {
        float sm = 0.f;
#pragma unroll
        for (int j = 0; j < 4; ++j) sm += s_lds[lrow][cl + 32 * j];
        sm += __shfl_xor(sm, 1, 64);
        sm += __shfl_xor(sm, 2, 64);
        sm += __shfl_xor(sm, 4, 64);
        sm += __shfl_xor(sm, 8, 64);
        sm += __shfl_xor(sm, 16, 64);
        float mean = sm * (1.0f / HH);
        float vr = 0.f;
#pragma unroll
        for (int j = 0; j < 4; ++j) {
            float d = s_lds[lrow][cl + 32 * j] - mean;
            vr += d * d;
        }
        vr += __shfl_xor(vr, 1, 64);
        vr += __shfl_xor(vr, 2, 64);
        vr += __shfl_xor(vr, 4, 64);
        vr += __shfl_xor(vr, 8, 64);
        vr += __shfl_xor(vr, 16, 64);
        float rstd = rsqrtf(vr * (1.0f / HH) + 1e-8f);
#pragma unroll
        for (int j = 0; j < 4; ++j) {
            int c = cl + 32 * j;
            s_lds[lrow][c] = (s_lds[lrow][c] - mean) * rstd * g1[c] + be1[c];
        }
    }
    __syncthreads();
    // GEMM1 + relu
    int c = t & 127, rg = t >> 7;
    float acc[4] = {0.f, 0.f, 0.f, 0.f};
    const float4* w14 = (const float4*)(W1 + c * HH);
#pragma unroll 4
    for (int k4 = 0; k4 < HH / 4; ++k4) {
        float4 ww = w14[k4];
#pragma unroll
        for (int r = 0; r < 4; ++r) {
            float4 s = *(const float4*)&s_lds[rg * 4 + r][k4 * 4];
            acc[r] += s.x * ww.x + s.y * ww.y + s.z * ww.z + s.w * ww.w;
        }
    }
#pragma unroll
    for (int r = 0; r < 4; ++r) h_lds[rg * 4 + r][c] = fmaxf(acc[r] + b1[c], 0.f);
    __syncthreads();
    // GEMM2 into registers
#pragma unroll
    for (int r = 0; r < 4; ++r) acc[r] = 0.f;
    const float4* w24 = (const float4*)(W2 + c * HH);
#pragma unroll 4
    for (int k4 = 0; k4 < HH / 4; ++k4) {
        float4 ww = w24[k4];
#pragma unroll
        for (int r = 0; r < 4; ++r) {
            float4 s = *(const float4*)&h_lds[rg * 4 + r][k4 * 4];
            acc[r] += s.x * ww.x + s.y * ww.y + s.z * ww.z + s.w * ww.w;
        }
    }
    __syncthreads();   // h_lds reads done; reuse for x2 = s1 + ffn
#pragma unroll
    for (int r = 0; r < 4; ++r)
        h_lds[rg * 4 + r][c] = s_lds[rg * 4 + r][c] + acc[r] + b2[c];
    __syncthreads();
    // LN2 + keep, write seqs
    {
        float sm = 0.f;
#pragma unroll
        for (int j = 0; j < 4; ++j) sm += h_lds[lrow][cl + 32 * j];
        sm += __shfl_xor(sm, 1, 64);
        sm += __shfl_xor(sm, 2, 64);
        sm += __shfl_xor(sm, 4, 64);
        sm += __shfl_xor(sm, 8, 64);
        sm += __shfl_xor(sm, 16, 64);
        float mean = sm * (1.0f / HH);
        float vr = 0.f;
#pragma unroll
        for (int j = 0; j < 4; ++j) {
            float d = h_lds[lrow][cl + 32 * j] - mean;
            vr += d * d;
        }
        vr += __shfl_xor(vr, 1, 64);
        vr += __shfl_xor(vr, 2, 64);
        vr += __shfl_xor(vr, 4, 64);
        vr += __shfl_xor(vr, 8, 64);
        vr += __shfl_xor(vr, 16, 64);
        float rstd = rsqrtf(vr * (1.0f / HH) + 1e-8f);
        float keep = (log_seqs[r0g + lrow] != 0) ? 1.0f : 0.0f;
#pragma unroll
        for (int j = 0; j < 4; ++j) {
            int cc = cl + 32 * j;
            float y = (h_lds[lrow][cc] - mean) * rstd * g2[cc] + be2[cc];
            seqs[(r0g + lrow) * HH + cc] = y * keep;
        }
    }
}

// ---------------- final LN + logits ----------------
__global__ void k_final(const float* __restrict__ seqs,
                        const float* __restrict__ lnf_g, const float* __restrict__ lnf_b,
                        const float* __restrict__ item_emb,
                        const int* __restrict__ pos_seqs, const int* __restrict__ neg_seqs,
                        float* __restrict__ out) {
    __shared__ float red[2];
    int row = blockIdx.x;
    int t = threadIdx.x;
    float x = seqs[row * HH + t];
    float m = x;
    m += __shfl_xor(m, 1, 64); m += __shfl_xor(m, 2, 64); m += __shfl_xor(m, 4, 64);
    m += __shfl_xor(m, 8, 64); m += __shfl_xor(m, 16, 64); m += __shfl_xor(m, 32, 64);
    if ((t & 63) == 0) red[t >> 6] = m;
    __syncthreads();
    m = (red[0] + red[1]) * (1.0f / HH);
    float d = x - m;
    __syncthreads();
    float v2 = d * d;
    v2 += __shfl_xor(v2, 1, 64); v2 += __shfl_xor(v2, 2, 64); v2 += __shfl_xor(v2, 4, 64);
    v2 += __shfl_xor(v2, 8, 64); v2 += __shfl_xor(v2, 16, 64); v2 += __shfl_xor(v2, 32, 64);
    if ((t & 63) == 0) red[t >> 6] = v2;
    __syncthreads();
    float var = (red[0] + red[1]) * (1.0f / HH);
    float lf = d * rsqrtf(var + 1e-8f) * lnf_g[t] + lnf_b[t];
    int pid = pos_seqs[row];
    int nid = neg_seqs[row];
    float pp = lf * item_emb[pid * HH + t];
    float nn = lf * item_emb[nid * HH + t];
    __syncthreads();
    float ps = pp;
    ps += __shfl_xor(ps, 1, 64); ps += __shfl_xor(ps, 2, 64); ps += __shfl_xor(ps, 4, 64);
    ps += __shfl_xor(ps, 8, 64); ps += __shfl_xor(ps, 16, 64); ps += __shfl_xor(ps, 32, 64);
    if ((t & 63) == 0) red[t >> 6] = ps;
    __syncthreads();
    float ptot = red[0] + red[1];
    __syncthreads();
    float ns = nn;
    ns += __shfl_xor(ns, 1, 64); ns += __shfl_xor(ns, 2, 64); ns += __shfl_xor(ns, 4, 64);
    ns += __shfl_xor(ns, 8, 64); ns += __shfl_xor(ns, 16, 64); ns += __shfl_xor(ns, 32, 64);
    if ((t & 63) == 0) red[t >> 6] = ns;
    __syncthreads();
    float ntot = red[0] + red[1];
    if (t == 0) {
        out[row] = ptot;
        out[BB * LL + row] = ntot;
    }
}

extern "C" void kernel_launch(void* const* d_in, const int* in_sizes, int n_in,
                              void* d_out, int out_size, void* d_ws, size_t ws_size,
                              hipStream_t stream) {
    const int* log_seqs = (const int*)d_in[1];
    const int* tm       = (const int*)d_in[2];
    const int* pos_seqs = (const int*)d_in[3];
    const int* neg_seqs = (const int*)d_in[4];
    const float* item_emb = (const float*)d_in[5];
    const float* posK   = (const float*)d_in[6];
    const float* posV   = (const float*)d_in[7];
    const float* timeK  = (const float*)d_in[8];
    const float* timeV  = (const float*)d_in[9];
    const float* Wq = (const float*)d_in[10];
    const float* bq = (const float*)d_in[11];
    const float* Wk = (const float*)d_in[12];
    const float* bk = (const float*)d_in[13];
    const float* Wv = (const float*)d_in[14];
    const float* bv = (const float*)d_in[15];
    const float* ln1_g = (const float*)d_in[16];
    const float* ln1_b = (const float*)d_in[17];
    const float* W1 = (const float*)d_in[18];
    const float* b1 = (const float*)d_in[19];
    const float* W2 = (const float*)d_in[20];
    const float* b2 = (const float*)d_in[21];
    const float* ln2_g = (const float*)d_in[22];
    const float* ln2_b = (const float*)d_in[23];
    const float* lnf_g = (const float*)d_in[24];
    const float* lnf_b = (const float*)d_in[25];

    float* ws    = (float*)d_ws;
    float* seqs  = ws;                   // 409600 floats each
    float* Qb    = seqs + 409600;
    float* Kpb   = Qb + 409600;
    float* Vpb   = Kpb + 409600;
    float* AO    = Vpb + 409600;

    for (int i = 0; i < 2; ++i) {
        k_qkv<<<BB * LL / 16, 512, 0, stream>>>(seqs, log_seqs, item_emb, (i == 0) ? 1 : 0,
            Wq + i * HH * HH, bq + i * HH,
            Wk + i * HH * HH, bk + i * HH,
            Wv + i * HH * HH, bv + i * HH,
            posK, posV, Qb, Kpb, Vpb);
        k_attn<<<32 * NQT2, 256, 0, stream>>>(Qb, Kpb, Vpb, timeK, timeV,
                                              tm, log_seqs, AO);
        k_ffn_full<<<BB * LL / 8, 256, 0, stream>>>(seqs, AO,
            ln1_g + i * HH, ln1_b + i * HH,
            W1 + i * HH * HH, b1 + i * HH,
            W2 + i * HH * HH, b2 + i * HH,
            ln2_g + i * HH, ln2_b + i * HH, log_seqs);
    }
    k_final<<<BB * LL, HH, 0, stream>>>(seqs, lnf_g, lnf_b, item_emb,
                                        pos_seqs, neg_seqs, (float*)d_out);
}

// Round 6
// 198.392 us; speedup vs baseline: 1.2432x; 1.0399x over previous
//
#include <hip/hip_runtime.h>
#include <hip/hip_bf16.h>
#include <math.h>

#define BB 16
#define LL 200
#define HH 128
#define DD 64
#define QT2 8
#define NQT2 25         // 200/8 exact
#define NEGF -4294967295.0f
#define SQRTH 11.313708498984761f

// ---------------- QKV projection (16 rows/block, 512 threads), optional embed ----------------
__global__ __launch_bounds__(512) void k_qkv(float* __restrict__ seqs,
    const int* __restrict__ log_seqs, const float* __restrict__ item_emb, int do_embed,
    const float* __restrict__ Wq, const float* __restrict__ bq,
    const float* __restrict__ Wk, const float* __restrict__ bk,
    const float* __restrict__ Wv, const float* __restrict__ bv,
    const float* __restrict__ posK, const float* __restrict__ posV,
    float* __restrict__ Q, float* __restrict__ Kp, float* __restrict__ Vp) {
    __shared__ float s_lds[16][HH];
    int r0g = blockIdx.x * 16;
    int t = threadIdx.x;
    if (do_embed) {
        int r = t >> 5, d4 = t & 31;          // 16 rows x 32 float4
        int id = log_seqs[r0g + r];
        float4 v = make_float4(0.f, 0.f, 0.f, 0.f);
        if (id != 0) {
            v = ((const float4*)(item_emb + id * HH))[d4];
            v.x *= SQRTH; v.y *= SQRTH; v.z *= SQRTH; v.w *= SQRTH;
        }
        *(float4*)&s_lds[r][d4 * 4] = v;
        ((float4*)(seqs + r0g * HH))[t] = v;
    } else {
        ((float4*)s_lds)[t] = ((const float4*)(seqs + r0g * HH))[t];
    }
    __syncthreads();
    int c = t & 127, rg = t >> 7;
    float aq[4] = {0.f, 0.f, 0.f, 0.f};
    float ak[4] = {0.f, 0.f, 0.f, 0.f};
    float av[4] = {0.f, 0.f, 0.f, 0.f};
    const float4* wq4 = (const float4*)(Wq + c * HH);
    const float4* wk4 = (const float4*)(Wk + c * HH);
    const float4* wv4 = (const float4*)(Wv + c * HH);
#pragma unroll 4
    for (int k4 = 0; k4 < HH / 4; ++k4) {
        float4 wq = wq4[k4], wk = wk4[k4], wv = wv4[k4];
#pragma unroll
        for (int r = 0; r < 4; ++r) {
            float4 s = *(const float4*)&s_lds[rg * 4 + r][k4 * 4];
            aq[r] += s.x * wq.x + s.y * wq.y + s.z * wq.z + s.w * wq.w;
            ak[r] += s.x * wk.x + s.y * wk.y + s.z * wk.z + s.w * wk.w;
            av[r] += s.x * wv.x + s.y * wv.y + s.z * wv.z + s.w * wv.w;
        }
    }
#pragma unroll
    for (int r = 0; r < 4; ++r) {
        int row = r0g + rg * 4 + r;
        int l = row % LL;
        Q[row * HH + c]  = aq[r] + bq[c];
        Kp[row * HH + c] = ak[r] + bk[c] + posK[l * HH + c];
        Vp[row * HH + c] = av[r] + bv[c] + posV[l * HH + c];
    }
}

// ---------------- projK[bh,q,tt] = Q[b,q,h,:] . timeK[tt,h,:] ----------------
// grid = 32 bh * 13 qtiles(16); 256 threads: tq = t>>4, ttl = t&15
__global__ __launch_bounds__(256) void k_proj(const float* __restrict__ Q,
    const float* __restrict__ timeK, float* __restrict__ projK) {
    int bh = blockIdx.x / 13, qt = blockIdx.x % 13;
    int b = bh >> 1, h = bh & 1;
    int qlo = qt * 16;
    __shared__ float Qs[16][68];
    __shared__ float TK[32][68];
    int t = threadIdx.x;
    {
        int r = t >> 4, d4 = t & 15;
        int q = qlo + r;
        float4 v = make_float4(0.f, 0.f, 0.f, 0.f);
        if (q < LL) v = ((const float4*)(Q + (b * LL + q) * HH + h * DD))[d4];
        *(float4*)&Qs[r][d4 * 4] = v;
    }
    int tq = t >> 4, ttl = t & 15;
    int q = qlo + tq;
    for (int c = 0; c < 9; ++c) {
        int base = c * 32;
        __syncthreads();                 // protect TK (and Qs on c==0)
        for (int x = t; x < 512; x += 256) {
            int i = x >> 4, d4 = x & 15;
            int tt = base + i;
            if (tt < 257)
                *(float4*)&TK[i][d4 * 4] =
                    ((const float4*)(timeK + tt * HH + h * DD))[d4];
        }
        __syncthreads();
#pragma unroll
        for (int j = 0; j < 2; ++j) {
            int ti = ttl + 16 * j;
            int tt = base + ti;
            if (tt < 257 && q < LL) {
                float acc = 0.f;
#pragma unroll
                for (int d4 = 0; d4 < 16; ++d4) {
                    float4 qv = *(const float4*)&Qs[tq][d4 * 4];
                    float4 kv = *(const float4*)&TK[ti][d4 * 4];
                    acc += qv.x * kv.x + qv.y * kv.y + qv.z * kv.z + qv.w * kv.w;
                }
                projK[(bh * LL + q) * 257 + tt] = acc;
            }
        }
    }
}

// ---------------- fused scores + softmax + hist + PV ----------------
// grid = 32 bh * 25 qtiles(8); 256 threads: tq/g = t>>5, lane = t&31
// LDS: K_s[32][68] + W_T[457][12] (S rows 0..199, hist rows 200..456)
//      + proj_T[257][9] + ballot pad-mask  ~= 39.9 KB -> 4 blocks/CU
__global__ __launch_bounds__(256) void k_attn(
    const float* __restrict__ Q, const float* __restrict__ Kp, const float* __restrict__ Vp,
    const float* __restrict__ projK, const float* __restrict__ timeV,
    const int* __restrict__ tm, const int* __restrict__ log_seqs,
    float* __restrict__ attnout) {
    int bh = blockIdx.x / NQT2, qt = blockIdx.x % NQT2;
    int b = bh >> 1, h = bh & 1;
    int qlo = qt * QT2;
    __shared__ float K_s[32][68];
    __shared__ float smemW[457 * 12];        // W_T(i,j) = smemW[i*12+j]
    __shared__ float proj_T[257][9];
    __shared__ unsigned long long pm64[4];
    __shared__ int s_allmask;
#define WT(i, j) smemW[(i) * 12 + (j)]
    int t = threadIdx.x;
    int tq = t >> 5, lane = t & 31, g = tq;
    int q = qlo + tq;
    int qhi = qlo + QT2 - 1;

    // pad mask via wave ballot (t<200 valid)
    {
        bool keep = (t < LL) && (log_seqs[b * LL + t] != 0);
        unsigned long long ball = __ballot(keep);
        if ((t & 63) == 0) pm64[t >> 6] = ball;
    }
    if (t == 0) s_allmask = 0;
    // init W_T: S rows NEGF, hist rows 0
    for (int x = t; x < 200 * 12; x += 256) smemW[x] = NEGF;
    for (int x = 200 * 12 + t; x < 457 * 12; x += 256) smemW[x] = 0.f;
    // stage proj_T (coalesced global read, conflict-free stride-9 transpose write)
    {
        const float* pbase = projK + (bh * LL + qlo) * 257;
        for (int x = t; x < 8 * 257; x += 256) {
            int qq = x / 257, tt = x - qq * 257;
            proj_T[tt][qq] = pbase[x];
        }
    }
    // Q row into registers
    float4 qreg[16];
    {
        const float4* qp = (const float4*)(Q + (b * LL + q) * HH + h * DD);
#pragma unroll
        for (int d4 = 0; d4 < 16; ++d4) qreg[d4] = qp[d4];
    }
    const int* tmrow = tm + (b * LL + q) * LL;
    __syncthreads();

    // phase 1: scores (32-row K chunks)
    int nkc = (qhi >> 5) + 1;
    for (int kc = 0; kc < nkc; ++kc) {
        int kbase = kc * 32;
        for (int x = t; x < 512; x += 256) {
            int i = x >> 4, d4 = x & 15;
            int k = kbase + i;
            if (k < LL)
                *(float4*)&K_s[i][d4 * 4] =
                    ((const float4*)(Kp + (b * LL + k) * HH + h * DD))[d4];
        }
        __syncthreads();
        int k = kbase + lane;
        if (k <= q && ((pm64[k >> 6] >> (k & 63)) & 1ull)) {
            float acc = 0.f;
#pragma unroll
            for (int d4 = 0; d4 < 16; ++d4) {
                float4 kv = *(const float4*)&K_s[lane][d4 * 4];
                acc += qreg[d4].x * kv.x + qreg[d4].y * kv.y +
                       qreg[d4].z * kv.z + qreg[d4].w * kv.w;
            }
            WT(k, tq) = (acc + proj_T[tmrow[k]][tq]) * 0.125f;
        }
        __syncthreads();
    }

    // phase 2: softmax on column tq (rows 0..199) + hist scatter into rows 200+
    float mx = -INFINITY;
    for (int k = lane; k < LL; k += 32) mx = fmaxf(mx, WT(k, tq));
    mx = fmaxf(mx, __shfl_xor(mx, 1, 64));
    mx = fmaxf(mx, __shfl_xor(mx, 2, 64));
    mx = fmaxf(mx, __shfl_xor(mx, 4, 64));
    mx = fmaxf(mx, __shfl_xor(mx, 8, 64));
    mx = fmaxf(mx, __shfl_xor(mx, 16, 64));
    bool allmask = (mx == NEGF);
    float sum = 0.f;
    for (int k = lane; k < LL; k += 32) {
        float e = __expf(WT(k, tq) - mx);
        WT(k, tq) = e;
        sum += e;
    }
    sum += __shfl_xor(sum, 1, 64);
    sum += __shfl_xor(sum, 2, 64);
    sum += __shfl_xor(sum, 4, 64);
    sum += __shfl_xor(sum, 8, 64);
    sum += __shfl_xor(sum, 16, 64);
    float inv = 1.0f / sum;
    int klim = allmask ? LL : (q + 1);
    if (allmask && lane == 0) s_allmask = 1;
    for (int k = lane; k < LL; k += 32) {
        float p = WT(k, tq) * inv;
        WT(k, tq) = p;
        if (k < klim) atomicAdd(&WT(200 + tmrow[k], tq), p);
    }
    __syncthreads();

    // phase 3: PV — direct coalesced global reads of Vp/timeV, broadcast LDS weights
    int kmax = s_allmask ? LL : (qhi + 1);
    float a00=0.f,a01=0.f,a10=0.f,a11=0.f,a20=0.f,a21=0.f,a30=0.f,a31=0.f;
    float a40=0.f,a41=0.f,a50=0.f,a51=0.f,a60=0.f,a61=0.f,a70=0.f,a71=0.f;
#define PV_STEP(WROW, SRCPTR)                                            \
    {                                                                    \
        const float* wr = &WROW;                                         \
        float4 w0 = *(const float4*)wr;                                  \
        float4 w1 = *(const float4*)(wr + 4);                            \
        float2 vv = *(const float2*)(SRCPTR);                            \
        a00 += w0.x * vv.x; a01 += w0.x * vv.y;                          \
        a10 += w0.y * vv.x; a11 += w0.y * vv.y;                          \
        a20 += w0.z * vv.x; a21 += w0.z * vv.y;                          \
        a30 += w0.w * vv.x; a31 += w0.w * vv.y;                          \
        a40 += w1.x * vv.x; a41 += w1.x * vv.y;                          \
        a50 += w1.y * vv.x; a51 += w1.y * vv.y;                          \
        a60 += w1.z * vv.x; a61 += w1.z * vv.y;                          \
        a70 += w1.w * vv.x; a71 += w1.w * vv.y;                          \
    }
    for (int i = g; i < kmax; i += 8)
        PV_STEP(WT(i, 0), Vp + (b * LL + i) * HH + h * DD + lane * 2);
    for (int i = g; i < 257; i += 8)
        PV_STEP(WT(200 + i, 0), timeV + i * HH + h * DD + lane * 2);
#undef PV_STEP
    __syncthreads();
    // cross-group reduce via smemW scratch (4096 floats)
    float* part = smemW;
    part[g * 512 + 0 * 64 + lane * 2] = a00; part[g * 512 + 0 * 64 + lane * 2 + 1] = a01;
    part[g * 512 + 1 * 64 + lane * 2] = a10; part[g * 512 + 1 * 64 + lane * 2 + 1] = a11;
    part[g * 512 + 2 * 64 + lane * 2] = a20; part[g * 512 + 2 * 64 + lane * 2 + 1] = a21;
    part[g * 512 + 3 * 64 + lane * 2] = a30; part[g * 512 + 3 * 64 + lane * 2 + 1] = a31;
    part[g * 512 + 4 * 64 + lane * 2] = a40; part[g * 512 + 4 * 64 + lane * 2 + 1] = a41;
    part[g * 512 + 5 * 64 + lane * 2] = a50; part[g * 512 + 5 * 64 + lane * 2 + 1] = a51;
    part[g * 512 + 6 * 64 + lane * 2] = a60; part[g * 512 + 6 * 64 + lane * 2 + 1] = a61;
    part[g * 512 + 7 * 64 + lane * 2] = a70; part[g * 512 + 7 * 64 + lane * 2 + 1] = a71;
    __syncthreads();
    {
        float ox = 0.f, oy = 0.f;
#pragma unroll
        for (int gg = 0; gg < 8; ++gg) {
            ox += part[gg * 512 + tq * 64 + lane * 2];
            oy += part[gg * 512 + tq * 64 + lane * 2 + 1];
        }
        *(float2*)(attnout + (b * LL + q) * HH + h * DD + lane * 2) =
            make_float2(ox, oy);
    }
#undef WT
}

// ---------------- fused: s1 = LN1(seqs+AO); seqs = LN2(s1 + FFN(s1)) * keep ----------------
__global__ __launch_bounds__(256) void k_ffn_full(
    float* __restrict__ seqs, const float* __restrict__ AO,
    const float* __restrict__ g1, const float* __restrict__ be1,
    const float* __restrict__ W1, const float* __restrict__ b1,
    const float* __restrict__ W2, const float* __restrict__ b2,
    const float* __restrict__ g2, const float* __restrict__ be2,
    const int* __restrict__ log_seqs) {
    __shared__ float s_lds[8][HH];
    __shared__ float h_lds[8][HH];
    int r0g = blockIdx.x * 8;
    int t = threadIdx.x;
    {
        float4 a = ((const float4*)(seqs + r0g * HH))[t];
        float4 o = ((const float4*)(AO + r0g * HH))[t];
        a.x += o.x; a.y += o.y; a.z += o.z; a.w += o.w;
        ((float4*)s_lds)[t] = a;
    }
    __syncthreads();
    int w = t >> 6, lane = t & 63;
    int lrow = w * 2 + (lane >> 5), cl = lane & 31;
    {
        float sm = 0.f;
#pragma unroll
        for (int j = 0; j < 4; ++j) sm += s_lds[lrow][cl + 32 * j];
        sm += __shfl_xor(sm, 1, 64);
        sm += __shfl_xor(sm, 2, 64);
        sm += __shfl_xor(sm, 4, 64);
        sm += __shfl_xor(sm, 8, 64);
        sm += __shfl_xor(sm, 16, 64);
        float mean = sm * (1.0f / HH);
        float vr = 0.f;
#pragma unroll
        for (int j = 0; j < 4; ++j) {
            float d = s_lds[lrow][cl + 32 * j] - mean;
            vr += d * d;
        }
        vr += __shfl_xor(vr, 1, 64);
        vr += __shfl_xor(vr, 2, 64);
        vr += __shfl_xor(vr, 4, 64);
        vr += __shfl_xor(vr, 8, 64);
        vr += __shfl_xor(vr, 16, 64);
        float rstd = rsqrtf(vr * (1.0f / HH) + 1e-8f);
#pragma unroll
        for (int j = 0; j < 4; ++j) {
            int c = cl + 32 * j;
            s_lds[lrow][c] = (s_lds[lrow][c] - mean) * rstd * g1[c] + be1[c];
        }
    }
    __syncthreads();
    int c = t & 127, rg = t >> 7;
    float acc[4] = {0.f, 0.f, 0.f, 0.f};
    const float4* w14 = (const float4*)(W1 + c * HH);
#pragma unroll 4
    for (int k4 = 0; k4 < HH / 4; ++k4) {
        float4 ww = w14[k4];
#pragma unroll
        for (int r = 0; r < 4; ++r) {
            float4 s = *(const float4*)&s_lds[rg * 4 + r][k4 * 4];
            acc[r] += s.x * ww.x + s.y * ww.y + s.z * ww.z + s.w * ww.w;
        }
    }
#pragma unroll
    for (int r = 0; r < 4; ++r) h_lds[rg * 4 + r][c] = fmaxf(acc[r] + b1[c], 0.f);
    __syncthreads();
#pragma unroll
    for (int r = 0; r < 4; ++r) acc[r] = 0.f;
    const float4* w24 = (const float4*)(W2 + c * HH);
#pragma unroll 4
    for (int k4 = 0; k4 < HH / 4; ++k4) {
        float4 ww = w24[k4];
#pragma unroll
        for (int r = 0; r < 4; ++r) {
            float4 s = *(const float4*)&h_lds[rg * 4 + r][k4 * 4];
            acc[r] += s.x * ww.x + s.y * ww.y + s.z * ww.z + s.w * ww.w;
        }
    }
    __syncthreads();
#pragma unroll
    for (int r = 0; r < 4; ++r)
        h_lds[rg * 4 + r][c] = s_lds[rg * 4 + r][c] + acc[r] + b2[c];
    __syncthreads();
    {
        float sm = 0.f;
#pragma unroll
        for (int j = 0; j < 4; ++j) sm += h_lds[lrow][cl + 32 * j];
        sm += __shfl_xor(sm, 1, 64);
        sm += __shfl_xor(sm, 2, 64);
        sm += __shfl_xor(sm, 4, 64);
        sm += __shfl_xor(sm, 8, 64);
        sm += __shfl_xor(sm, 16, 64);
        float mean = sm * (1.0f / HH);
        float vr = 0.f;
#pragma unroll
        for (int j = 0; j < 4; ++j) {
            float d = h_lds[lrow][cl + 32 * j] - mean;
            vr += d * d;
        }
        vr += __shfl_xor(vr, 1, 64);
        vr += __shfl_xor(vr, 2, 64);
        vr += __shfl_xor(vr, 4, 64);
        vr += __shfl_xor(vr, 8, 64);
        vr += __shfl_xor(vr, 16, 64);
        float rstd = rsqrtf(vr * (1.0f / HH) + 1e-8f);
        float keep = (log_seqs[r0g + lrow] != 0) ? 1.0f : 0.0f;
#pragma unroll
        for (int j = 0; j < 4; ++j) {
            int cc = cl + 32 * j;
            float y = (h_lds[lrow][cc] - mean) * rstd * g2[cc] + be2[cc];
            seqs[(r0g + lrow) * HH + cc] = y * keep;
        }
    }
}

// ---------------- final LN + logits ----------------
__global__ void k_final(const float* __restrict__ seqs,
                        const float* __restrict__ lnf_g, const float* __restrict__ lnf_b,
                        const float* __restrict__ item_emb,
                        const int* __restrict__ pos_seqs, const int* __restrict__ neg_seqs,
                        float* __restrict__ out) {
    __shared__ float red[2];
    int row = blockIdx.x;
    int t = threadIdx.x;
    float x = seqs[row * HH + t];
    float m = x;
    m += __shfl_xor(m, 1, 64); m += __shfl_xor(m, 2, 64); m += __shfl_xor(m, 4, 64);
    m += __shfl_xor(m, 8, 64); m += __shfl_xor(m, 16, 64); m += __shfl_xor(m, 32, 64);
    if ((t & 63) == 0) red[t >> 6] = m;
    __syncthreads();
    m = (red[0] + red[1]) * (1.0f / HH);
    float d = x - m;
    __syncthreads();
    float v2 = d * d;
    v2 += __shfl_xor(v2, 1, 64); v2 += __shfl_xor(v2, 2, 64); v2 += __shfl_xor(v2, 4, 64);
    v2 += __shfl_xor(v2, 8, 64); v2 += __shfl_xor(v2, 16, 64); v2 += __shfl_xor(v2, 32, 64);
    if ((t & 63) == 0) red[t >> 6] = v2;
    __syncthreads();
    float var = (red[0] + red[1]) * (1.0f / HH);
    float lf = d * rsqrtf(var + 1e-8f) * lnf_g[t] + lnf_b[t];
    int pid = pos_seqs[row];
    int nid = neg_seqs[row];
    float pp = lf * item_emb[pid * HH + t];
    float nn = lf * item_emb[nid * HH + t];
    __syncthreads();
    float ps = pp;
    ps += __shfl_xor(ps, 1, 64); ps += __shfl_xor(ps, 2, 64); ps += __shfl_xor(ps, 4, 64);
    ps += __shfl_xor(ps, 8, 64); ps += __shfl_xor(ps, 16, 64); ps += __shfl_xor(ps, 32, 64);
    if ((t & 63) == 0) red[t >> 6] = ps;
    __syncthreads();
    float ptot = red[0] + red[1];
    __syncthreads();
    float ns = nn;
    ns += __shfl_xor(ns, 1, 64); ns += __shfl_xor(ns, 2, 64); ns += __shfl_xor(ns, 4, 64);
    ns += __shfl_xor(ns, 8, 64); ns += __shfl_xor(ns, 16, 64); ns += __shfl_xor(ns, 32, 64);
    if ((t & 63) == 0) red[t >> 6] = ns;
    __syncthreads();
    float ntot = red[0] + red[1];
    if (t == 0) {
        out[row] = ptot;
        out[BB * LL + row] = ntot;
    }
}

extern "C" void kernel_launch(void* const* d_in, const int* in_sizes, int n_in,
                              void* d_out, int out_size, void* d_ws, size_t ws_size,
                              hipStream_t stream) {
    const int* log_seqs = (const int*)d_in[1];
    const int* tm       = (const int*)d_in[2];
    const int* pos_seqs = (const int*)d_in[3];
    const int* neg_seqs = (const int*)d_in[4];
    const float* item_emb = (const float*)d_in[5];
    const float* posK   = (const float*)d_in[6];
    const float* posV   = (const float*)d_in[7];
    const float* timeK  = (const float*)d_in[8];
    const float* timeV  = (const float*)d_in[9];
    const float* Wq = (const float*)d_in[10];
    const float* bq = (const float*)d_in[11];
    const float* Wk = (const float*)d_in[12];
    const float* bk = (const float*)d_in[13];
    const float* Wv = (const float*)d_in[14];
    const float* bv = (const float*)d_in[15];
    const float* ln1_g = (const float*)d_in[16];
    const float* ln1_b = (const float*)d_in[17];
    const float* W1 = (const float*)d_in[18];
    const float* b1 = (const float*)d_in[19];
    const float* W2 = (const float*)d_in[20];
    const float* b2 = (const float*)d_in[21];
    const float* ln2_g = (const float*)d_in[22];
    const float* ln2_b = (const float*)d_in[23];
    const float* lnf_g = (const float*)d_in[24];
    const float* lnf_b = (const float*)d_in[25];

    float* ws    = (float*)d_ws;
    float* seqs  = ws;                   // 409600 floats each
    float* Qb    = seqs + 409600;
    float* Kpb   = Qb + 409600;
    float* Vpb   = Kpb + 409600;
    float* AO    = Vpb + 409600;
    float* projK = AO + 409600;          // 32*200*257 = 1,644,800

    for (int i = 0; i < 2; ++i) {
        k_qkv<<<BB * LL / 16, 512, 0, stream>>>(seqs, log_seqs, item_emb, (i == 0) ? 1 : 0,
            Wq + i * HH * HH, bq + i * HH,
            Wk + i * HH * HH, bk + i * HH,
            Wv + i * HH * HH, bv + i * HH,
            posK, posV, Qb, Kpb, Vpb);
        k_proj<<<32 * 13, 256, 0, stream>>>(Qb, timeK, projK);
        k_attn<<<32 * NQT2, 256, 0, stream>>>(Qb, Kpb, Vpb, projK, timeV,
                                              tm, log_seqs, AO);
        k_ffn_full<<<BB * LL / 8, 256, 0, stream>>>(seqs, AO,
            ln1_g + i * HH, ln1_b + i * HH,
            W1 + i * HH * HH, b1 + i * HH,
            W2 + i * HH * HH, b2 + i * HH,
            ln2_g + i * HH, ln2_b + i * HH, log_seqs);
    }
    k_final<<<BB * LL, HH, 0, stream>>>(seqs, lnf_g, lnf_b, item_emb,
                                        pos_seqs, neg_seqs, (float*)d_out);
}

// Round 7
// 191.410 us; speedup vs baseline: 1.2885x; 1.0365x over previous
//
#include <hip/hip_runtime.h>
#include <hip/hip_bf16.h>
#include <math.h>

#define BB 16
#define LL 200
#define HH 128
#define DD 64
#define QT2 8
#define NQT2 25         // 200/8 exact
#define NEGF -4294967295.0f
#define SQRTH 11.313708498984761f

// ---------------- QKV projection + timeK projection (16 rows/block, 512 threads) ----------------
// phase A: Q/Kp/Vp = s@W^T + b (+pos); Q also parked in LDS
// phase B: projK[bh,row,tt] = Q[row,h,:] . timeK[tt,h,:], timeK LDS-staged 32 rows at a time
__global__ __launch_bounds__(512) void k_qkv_proj(float* __restrict__ seqs,
    const int* __restrict__ log_seqs, const float* __restrict__ item_emb, int do_embed,
    const float* __restrict__ Wq, const float* __restrict__ bq,
    const float* __restrict__ Wk, const float* __restrict__ bk,
    const float* __restrict__ Wv, const float* __restrict__ bv,
    const float* __restrict__ posK, const float* __restrict__ posV,
    const float* __restrict__ timeK,
    float* __restrict__ Q, float* __restrict__ Kp, float* __restrict__ Vp,
    float* __restrict__ projK) {
    __shared__ float s_lds[16][HH];       // seqs rows, later Q rows
    __shared__ float TK[32][132];         // timeK chunk, full 128 width (pad 132)
    int r0g = blockIdx.x * 16;
    int t = threadIdx.x;
    if (do_embed) {
        int r = t >> 5, d4 = t & 31;      // 16 rows x 32 float4
        int id = log_seqs[r0g + r];
        float4 v = make_float4(0.f, 0.f, 0.f, 0.f);
        if (id != 0) {
            v = ((const float4*)(item_emb + id * HH))[d4];
            v.x *= SQRTH; v.y *= SQRTH; v.z *= SQRTH; v.w *= SQRTH;
        }
        *(float4*)&s_lds[r][d4 * 4] = v;
        ((float4*)(seqs + r0g * HH))[t] = v;
    } else {
        ((float4*)s_lds)[t] = ((const float4*)(seqs + r0g * HH))[t];
    }
    __syncthreads();
    int c = t & 127, rg = t >> 7;
    float aq[4] = {0.f, 0.f, 0.f, 0.f};
    float ak[4] = {0.f, 0.f, 0.f, 0.f};
    float av[4] = {0.f, 0.f, 0.f, 0.f};
    const float4* wq4 = (const float4*)(Wq + c * HH);
    const float4* wk4 = (const float4*)(Wk + c * HH);
    const float4* wv4 = (const float4*)(Wv + c * HH);
#pragma unroll 4
    for (int k4 = 0; k4 < HH / 4; ++k4) {
        float4 wq = wq4[k4], wk = wk4[k4], wv = wv4[k4];
#pragma unroll
        for (int r = 0; r < 4; ++r) {
            float4 s = *(const float4*)&s_lds[rg * 4 + r][k4 * 4];
            aq[r] += s.x * wq.x + s.y * wq.y + s.z * wq.z + s.w * wq.w;
            ak[r] += s.x * wk.x + s.y * wk.y + s.z * wk.z + s.w * wk.w;
            av[r] += s.x * wv.x + s.y * wv.y + s.z * wv.z + s.w * wv.w;
        }
    }
    __syncthreads();                       // all seqs reads done before Q overwrite
#pragma unroll
    for (int r = 0; r < 4; ++r) {
        int row = r0g + rg * 4 + r;
        int l = row % LL;
        float qv = aq[r] + bq[c];
        Q[row * HH + c]  = qv;
        s_lds[rg * 4 + r][c] = qv;         // park Q for phase B
        Kp[row * HH + c] = ak[r] + bk[c] + posK[l * HH + c];
        Vp[row * HH + c] = av[r] + bv[c] + posV[l * HH + c];
    }
    // phase B: proj both heads, 9 chunks of 32 tt rows
    int tq = t >> 5, ttl = t & 31;
    int row = r0g + tq;
    int brow = row / LL, lrow = row - brow * LL;
    for (int ch = 0; ch < 9; ++ch) {
        int base = ch * 32;
        __syncthreads();                   // prior chunk consumed (+Q stores visible on ch==0)
        for (int x = t; x < 32 * 32; x += 512) {
            int i = x >> 5, d4 = x & 31;
            int tt = base + i;
            if (tt < 257)
                *(float4*)&TK[i][d4 * 4] = ((const float4*)(timeK + tt * HH))[d4];
        }
        __syncthreads();
        int tt = base + ttl;
        if (tt < 257) {
#pragma unroll
            for (int h = 0; h < 2; ++h) {
                float acc = 0.f;
#pragma unroll
                for (int d4 = 0; d4 < 16; ++d4) {
                    float4 qv = *(const float4*)&s_lds[tq][h * DD + d4 * 4];
                    float4 kv = *(const float4*)&TK[ttl][h * DD + d4 * 4];
                    acc += qv.x * kv.x + qv.y * kv.y + qv.z * kv.z + qv.w * kv.w;
                }
                projK[((brow * 2 + h) * LL + lrow) * 257 + tt] = acc;
            }
        }
    }
}

// ---------------- fused scores + softmax + hist + PV ----------------
// grid = 32 bh * 25 qtiles(8); 256 threads: tq/g = t>>5, lane = t&31
__global__ __launch_bounds__(256) void k_attn(
    const float* __restrict__ Q, const float* __restrict__ Kp, const float* __restrict__ Vp,
    const float* __restrict__ projK, const float* __restrict__ timeV,
    const int* __restrict__ tm, const int* __restrict__ log_seqs,
    float* __restrict__ attnout) {
    int bh = blockIdx.x / NQT2, qt = blockIdx.x % NQT2;
    int b = bh >> 1, h = bh & 1;
    int qlo = qt * QT2;
    __shared__ float K_s[32][68];
    __shared__ float smemW[457 * 12];        // W_T(i,j) = smemW[i*12+j]
    __shared__ float proj_T[257][9];
    __shared__ unsigned long long pm64[4];
    __shared__ int s_allmask;
#define WT(i, j) smemW[(i) * 12 + (j)]
    int t = threadIdx.x;
    int tq = t >> 5, lane = t & 31, g = tq;
    int q = qlo + tq;
    int qhi = qlo + QT2 - 1;

    {
        bool keep = (t < LL) && (log_seqs[b * LL + t] != 0);
        unsigned long long ball = __ballot(keep);
        if ((t & 63) == 0) pm64[t >> 6] = ball;
    }
    if (t == 0) s_allmask = 0;
    for (int x = t; x < 200 * 12; x += 256) smemW[x] = NEGF;
    for (int x = 200 * 12 + t; x < 457 * 12; x += 256) smemW[x] = 0.f;
    {
        const float* pbase = projK + (bh * LL + qlo) * 257;
        for (int x = t; x < 8 * 257; x += 256) {
            int qq = x / 257, tt = x - qq * 257;
            proj_T[tt][qq] = pbase[x];
        }
    }
    float4 qreg[16];
    {
        const float4* qp = (const float4*)(Q + (b * LL + q) * HH + h * DD);
#pragma unroll
        for (int d4 = 0; d4 < 16; ++d4) qreg[d4] = qp[d4];
    }
    const int* tmrow = tm + (b * LL + q) * LL;
    __syncthreads();

    // phase 1: scores (32-row K chunks)
    int nkc = (qhi >> 5) + 1;
    for (int kc = 0; kc < nkc; ++kc) {
        int kbase = kc * 32;
        for (int x = t; x < 512; x += 256) {
            int i = x >> 4, d4 = x & 15;
            int k = kbase + i;
            if (k < LL)
                *(float4*)&K_s[i][d4 * 4] =
                    ((const float4*)(Kp + (b * LL + k) * HH + h * DD))[d4];
        }
        __syncthreads();
        int k = kbase + lane;
        if (k <= q && ((pm64[k >> 6] >> (k & 63)) & 1ull)) {
            float acc = 0.f;
#pragma unroll
            for (int d4 = 0; d4 < 16; ++d4) {
                float4 kv = *(const float4*)&K_s[lane][d4 * 4];
                acc += qreg[d4].x * kv.x + qreg[d4].y * kv.y +
                       qreg[d4].z * kv.z + qreg[d4].w * kv.w;
            }
            WT(k, tq) = (acc + proj_T[tmrow[k]][tq]) * 0.125f;
        }
        __syncthreads();
    }

    // phase 2: softmax + hist scatter
    float mx = -INFINITY;
    for (int k = lane; k < LL; k += 32) mx = fmaxf(mx, WT(k, tq));
    mx = fmaxf(mx, __shfl_xor(mx, 1, 64));
    mx = fmaxf(mx, __shfl_xor(mx, 2, 64));
    mx = fmaxf(mx, __shfl_xor(mx, 4, 64));
    mx = fmaxf(mx, __shfl_xor(mx, 8, 64));
    mx = fmaxf(mx, __shfl_xor(mx, 16, 64));
    bool allmask = (mx == NEGF);
    float sum = 0.f;
    for (int k = lane; k < LL; k += 32) {
        float e = __expf(WT(k, tq) - mx);
        WT(k, tq) = e;
        sum += e;
    }
    sum += __shfl_xor(sum, 1, 64);
    sum += __shfl_xor(sum, 2, 64);
    sum += __shfl_xor(sum, 4, 64);
    sum += __shfl_xor(sum, 8, 64);
    sum += __shfl_xor(sum, 16, 64);
    float inv = 1.0f / sum;
    int klim = allmask ? LL : (q + 1);
    if (allmask && lane == 0) s_allmask = 1;
    for (int k = lane; k < LL; k += 32) {
        float p = WT(k, tq) * inv;
        WT(k, tq) = p;
        if (k < klim) atomicAdd(&WT(200 + tmrow[k], tq), p);
    }
    __syncthreads();

    // phase 3: PV — direct coalesced global reads, broadcast LDS weights
    int kmax = s_allmask ? LL : (qhi + 1);
    float a00=0.f,a01=0.f,a10=0.f,a11=0.f,a20=0.f,a21=0.f,a30=0.f,a31=0.f;
    float a40=0.f,a41=0.f,a50=0.f,a51=0.f,a60=0.f,a61=0.f,a70=0.f,a71=0.f;
#define PV_STEP(WROW, SRCPTR)                                            \
    {                                                                    \
        const float* wr = &WROW;                                         \
        float4 w0 = *(const float4*)wr;                                  \
        float4 w1 = *(const float4*)(wr + 4);                            \
        float2 vv = *(const float2*)(SRCPTR);                            \
        a00 += w0.x * vv.x; a01 += w0.x * vv.y;                          \
        a10 += w0.y * vv.x; a11 += w0.y * vv.y;                          \
        a20 += w0.z * vv.x; a21 += w0.z * vv.y;                          \
        a30 += w0.w * vv.x; a31 += w0.w * vv.y;                          \
        a40 += w1.x * vv.x; a41 += w1.x * vv.y;                          \
        a50 += w1.y * vv.x; a51 += w1.y * vv.y;                          \
        a60 += w1.z * vv.x; a61 += w1.z * vv.y;                          \
        a70 += w1.w * vv.x; a71 += w1.w * vv.y;                          \
    }
    for (int i = g; i < kmax; i += 8)
        PV_STEP(WT(i, 0), Vp + (b * LL + i) * HH + h * DD + lane * 2);
    for (int i = g; i < 257; i += 8)
        PV_STEP(WT(200 + i, 0), timeV + i * HH + h * DD + lane * 2);
#undef PV_STEP
    __syncthreads();
    float* part = smemW;
    part[g * 512 + 0 * 64 + lane * 2] = a00; part[g * 512 + 0 * 64 + lane * 2 + 1] = a01;
    part[g * 512 + 1 * 64 + lane * 2] = a10; part[g * 512 + 1 * 64 + lane * 2 + 1] = a11;
    part[g * 512 + 2 * 64 + lane * 2] = a20; part[g * 512 + 2 * 64 + lane * 2 + 1] = a21;
    part[g * 512 + 3 * 64 + lane * 2] = a30; part[g * 512 + 3 * 64 + lane * 2 + 1] = a31;
    part[g * 512 + 4 * 64 + lane * 2] = a40; part[g * 512 + 4 * 64 + lane * 2 + 1] = a41;
    part[g * 512 + 5 * 64 + lane * 2] = a50; part[g * 512 + 5 * 64 + lane * 2 + 1] = a51;
    part[g * 512 + 6 * 64 + lane * 2] = a60; part[g * 512 + 6 * 64 + lane * 2 + 1] = a61;
    part[g * 512 + 7 * 64 + lane * 2] = a70; part[g * 512 + 7 * 64 + lane * 2 + 1] = a71;
    __syncthreads();
    {
        float ox = 0.f, oy = 0.f;
#pragma unroll
        for (int gg = 0; gg < 8; ++gg) {
            ox += part[gg * 512 + tq * 64 + lane * 2];
            oy += part[gg * 512 + tq * 64 + lane * 2 + 1];
        }
        *(float2*)(attnout + (b * LL + q) * HH + h * DD + lane * 2) =
            make_float2(ox, oy);
    }
#undef WT
}

// ---------------- fused: s1=LN1(seqs+AO); x2=s1+FFN(s1); seqs=LN2(x2)*keep
//                  (+ final layer: lnf LayerNorm + pos/neg logits) ----------------
__global__ __launch_bounds__(512) void k_ffn_full(
    float* __restrict__ seqs, const float* __restrict__ AO,
    const float* __restrict__ g1, const float* __restrict__ be1,
    const float* __restrict__ W1, const float* __restrict__ b1,
    const float* __restrict__ W2, const float* __restrict__ b2,
    const float* __restrict__ g2, const float* __restrict__ be2,
    const int* __restrict__ log_seqs, int do_final,
    const float* __restrict__ lnf_g, const float* __restrict__ lnf_b,
    const float* __restrict__ item_emb,
    const int* __restrict__ pos_seqs, const int* __restrict__ neg_seqs,
    float* __restrict__ out) {
    __shared__ float s_lds[16][HH];
    __shared__ float h_lds[16][HH];
    int r0g = blockIdx.x * 16;
    int t = threadIdx.x;
    {
        float4 a = ((const float4*)(seqs + r0g * HH))[t];
        float4 o = ((const float4*)(AO + r0g * HH))[t];
        a.x += o.x; a.y += o.y; a.z += o.z; a.w += o.w;
        ((float4*)s_lds)[t] = a;
    }
    __syncthreads();
    int w = t >> 6, lane = t & 63;
    int lrow = w * 2 + (lane >> 5), cl = lane & 31;
    // LN1 in-place
    {
        float sm = 0.f;
#pragma unroll
        for (int j = 0; j < 4; ++j) sm += s_lds[lrow][cl + 32 * j];
        sm += __shfl_xor(sm, 1, 64);
        sm += __shfl_xor(sm, 2, 64);
        sm += __shfl_xor(sm, 4, 64);
        sm += __shfl_xor(sm, 8, 64);
        sm += __shfl_xor(sm, 16, 64);
        float mean = sm * (1.0f / HH);
        float vr = 0.f;
#pragma unroll
        for (int j = 0; j < 4; ++j) {
            float d = s_lds[lrow][cl + 32 * j] - mean;
            vr += d * d;
        }
        vr += __shfl_xor(vr, 1, 64);
        vr += __shfl_xor(vr, 2, 64);
        vr += __shfl_xor(vr, 4, 64);
        vr += __shfl_xor(vr, 8, 64);
        vr += __shfl_xor(vr, 16, 64);
        float rstd = rsqrtf(vr * (1.0f / HH) + 1e-8f);
#pragma unroll
        for (int j = 0; j < 4; ++j) {
            int c = cl + 32 * j;
            s_lds[lrow][c] = (s_lds[lrow][c] - mean) * rstd * g1[c] + be1[c];
        }
    }
    __syncthreads();
    // GEMM1 + relu
    int c = t & 127, rg = t >> 7;
    float acc[4] = {0.f, 0.f, 0.f, 0.f};
    const float4* w14 = (const float4*)(W1 + c * HH);
#pragma unroll 4
    for (int k4 = 0; k4 < HH / 4; ++k4) {
        float4 ww = w14[k4];
#pragma unroll
        for (int r = 0; r < 4; ++r) {
            float4 s = *(const float4*)&s_lds[rg * 4 + r][k4 * 4];
            acc[r] += s.x * ww.x + s.y * ww.y + s.z * ww.z + s.w * ww.w;
        }
    }
#pragma unroll
    for (int r = 0; r < 4; ++r) h_lds[rg * 4 + r][c] = fmaxf(acc[r] + b1[c], 0.f);
    __syncthreads();
    // GEMM2
#pragma unroll
    for (int r = 0; r < 4; ++r) acc[r] = 0.f;
    const float4* w24 = (const float4*)(W2 + c * HH);
#pragma unroll 4
    for (int k4 = 0; k4 < HH / 4; ++k4) {
        float4 ww = w24[k4];
#pragma unroll
        for (int r = 0; r < 4; ++r) {
            float4 s = *(const float4*)&h_lds[rg * 4 + r][k4 * 4];
            acc[r] += s.x * ww.x + s.y * ww.y + s.z * ww.z + s.w * ww.w;
        }
    }
    __syncthreads();
#pragma unroll
    for (int r = 0; r < 4; ++r)
        h_lds[rg * 4 + r][c] = s_lds[rg * 4 + r][c] + acc[r] + b2[c];
    __syncthreads();
    // LN2 (+ keep); final layer additionally: lnf LN + logits
    {
        float sm = 0.f;
#pragma unroll
        for (int j = 0; j < 4; ++j) sm += h_lds[lrow][cl + 32 * j];
        sm += __shfl_xor(sm, 1, 64);
        sm += __shfl_xor(sm, 2, 64);
        sm += __shfl_xor(sm, 4, 64);
        sm += __shfl_xor(sm, 8, 64);
        sm += __shfl_xor(sm, 16, 64);
        float mean = sm * (1.0f / HH);
        float vr = 0.f;
#pragma unroll
        for (int j = 0; j < 4; ++j) {
            float d = h_lds[lrow][cl + 32 * j] - mean;
            vr += d * d;
        }
        vr += __shfl_xor(vr, 1, 64);
        vr += __shfl_xor(vr, 2, 64);
        vr += __shfl_xor(vr, 4, 64);
        vr += __shfl_xor(vr, 8, 64);
        vr += __shfl_xor(vr, 16, 64);
        float rstd = rsqrtf(vr * (1.0f / HH) + 1e-8f);
        int row = r0g + lrow;
        float keep = (log_seqs[row] != 0) ? 1.0f : 0.0f;
        float y2[4];
#pragma unroll
        for (int j = 0; j < 4; ++j) {
            int cc = cl + 32 * j;
            y2[j] = ((h_lds[lrow][cc] - mean) * rstd * g2[cc] + be2[cc]) * keep;
        }
        if (!do_final) {
#pragma unroll
            for (int j = 0; j < 4; ++j)
                seqs[row * HH + cl + 32 * j] = y2[j];
        } else {
            // final LayerNorm (lnf) on y2, then pos/neg logits
            float sm2 = y2[0] + y2[1] + y2[2] + y2[3];
            sm2 += __shfl_xor(sm2, 1, 64);
            sm2 += __shfl_xor(sm2, 2, 64);
            sm2 += __shfl_xor(sm2, 4, 64);
            sm2 += __shfl_xor(sm2, 8, 64);
            sm2 += __shfl_xor(sm2, 16, 64);
            float mean2 = sm2 * (1.0f / HH);
            float vr2 = 0.f;
#pragma unroll
            for (int j = 0; j < 4; ++j) {
                float d = y2[j] - mean2;
                vr2 += d * d;
            }
            vr2 += __shfl_xor(vr2, 1, 64);
            vr2 += __shfl_xor(vr2, 2, 64);
            vr2 += __shfl_xor(vr2, 4, 64);
            vr2 += __shfl_xor(vr2, 8, 64);
            vr2 += __shfl_xor(vr2, 16, 64);
            float rstd2 = rsqrtf(vr2 * (1.0f / HH) + 1e-8f);
            int pid = pos_seqs[row];
            int nid = neg_seqs[row];
            float pp = 0.f, nn = 0.f;
#pragma unroll
            for (int j = 0; j < 4; ++j) {
                int cc = cl + 32 * j;
                float lf = (y2[j] - mean2) * rstd2 * lnf_g[cc] + lnf_b[cc];
                pp += lf * item_emb[pid * HH + cc];
                nn += lf * item_emb[nid * HH + cc];
            }
            pp += __shfl_xor(pp, 1, 64);
            pp += __shfl_xor(pp, 2, 64);
            pp += __shfl_xor(pp, 4, 64);
            pp += __shfl_xor(pp, 8, 64);
            pp += __shfl_xor(pp, 16, 64);
            nn += __shfl_xor(nn, 1, 64);
            nn += __shfl_xor(nn, 2, 64);
            nn += __shfl_xor(nn, 4, 64);
            nn += __shfl_xor(nn, 8, 64);
            nn += __shfl_xor(nn, 16, 64);
            if (cl == 0) {
                out[row] = pp;
                out[BB * LL + row] = nn;
            }
        }
    }
}

extern "C" void kernel_launch(void* const* d_in, const int* in_sizes, int n_in,
                              void* d_out, int out_size, void* d_ws, size_t ws_size,
                              hipStream_t stream) {
    const int* log_seqs = (const int*)d_in[1];
    const int* tm       = (const int*)d_in[2];
    const int* pos_seqs = (const int*)d_in[3];
    const int* neg_seqs = (const int*)d_in[4];
    const float* item_emb = (const float*)d_in[5];
    const float* posK   = (const float*)d_in[6];
    const float* posV   = (const float*)d_in[7];
    const float* timeK  = (const float*)d_in[8];
    const float* timeV  = (const float*)d_in[9];
    const float* Wq = (const float*)d_in[10];
    const float* bq = (const float*)d_in[11];
    const float* Wk = (const float*)d_in[12];
    const float* bk = (const float*)d_in[13];
    const float* Wv = (const float*)d_in[14];
    const float* bv = (const float*)d_in[15];
    const float* ln1_g = (const float*)d_in[16];
    const float* ln1_b = (const float*)d_in[17];
    const float* W1 = (const float*)d_in[18];
    const float* b1 = (const float*)d_in[19];
    const float* W2 = (const float*)d_in[20];
    const float* b2 = (const float*)d_in[21];
    const float* ln2_g = (const float*)d_in[22];
    const float* ln2_b = (const float*)d_in[23];
    const float* lnf_g = (const float*)d_in[24];
    const float* lnf_b = (const float*)d_in[25];

    float* ws    = (float*)d_ws;
    float* seqs  = ws;                   // 409600 floats each
    float* Qb    = seqs + 409600;
    float* Kpb   = Qb + 409600;
    float* Vpb   = Kpb + 409600;
    float* AO    = Vpb + 409600;
    float* projK = AO + 409600;          // 32*200*257 = 1,644,800

    for (int i = 0; i < 2; ++i) {
        k_qkv_proj<<<BB * LL / 16, 512, 0, stream>>>(seqs, log_seqs, item_emb,
            (i == 0) ? 1 : 0,
            Wq + i * HH * HH, bq + i * HH,
            Wk + i * HH * HH, bk + i * HH,
            Wv + i * HH * HH, bv + i * HH,
            posK, posV, timeK, Qb, Kpb, Vpb, projK);
        k_attn<<<32 * NQT2, 256, 0, stream>>>(Qb, Kpb, Vpb, projK, timeV,
                                              tm, log_seqs, AO);
        k_ffn_full<<<BB * LL / 16, 512, 0, stream>>>(seqs, AO,
            ln1_g + i * HH, ln1_b + i * HH,
            W1 + i * HH * HH, b1 + i * HH,
            W2 + i * HH * HH, b2 + i * HH,
            ln2_g + i * HH, ln2_b + i * HH, log_seqs,
            (i == 1) ? 1 : 0, lnf_g, lnf_b, item_emb,
            pos_seqs, neg_seqs, (float*)d_out);
    }
}